// Round 21
// baseline (77.176 us; speedup 1.0000x reference)
//
#include <hip/hip_runtime.h>
#include <hip/hip_bf16.h>
#include <math.h>

#define BB   2
#define NN   8192
#define SS   1024
#define KK   32
#define HID  256
#define NTOK (BB * SS)
#define SENT 0xFFFFFFFFFFFFFFFFULL
#define LDB  264       // padded LDS row stride (bf16 elems)
#define WFE  65536     // frag elements per matrix copy (256*256)
#define PREPB 512      // prep blocks (256 thr each) fused ahead of knn grid
#define MT   3         // tokens per mlp block (M = 96)

typedef unsigned long long u64;
typedef unsigned int       u32;
typedef short bf16x8 __attribute__((ext_vector_type(8)));
typedef float f32x4  __attribute__((ext_vector_type(4)));

// compare-swap carry chain step
#define CSW(SI) { const u64 mn = x < (SI) ? x : (SI); const u64 mx = x < (SI) ? (SI) : x; (SI) = mn; x = mx; }
#define INS5(KV) { u64 x = (KV); CSW(s0) CSW(s1) CSW(s2) CSW(s3) CSW(s4) }
#define INS3HI(KV) { u64 x = (KV); CSW(s5) CSW(s6) CSW(s7) }
#define INS8(KV) { u64 x = (KV); CSW(s0) CSW(s1) CSW(s2) CSW(s3) CSW(s4) CSW(s5) CSW(s6) CSW(s7) }

#define DIST_KEY(i, kv)                                                        \
    const float dx = __fsub_rn(sx, posb[(i)*3 + 0]);                           \
    const float dy = __fsub_rn(sy, posb[(i)*3 + 1]);                           \
    const float dz = __fsub_rn(sz, posb[(i)*3 + 2]);                           \
    const float sq = __fadd_rn(__fadd_rn(__fmul_rn(dx,dx), __fmul_rn(dy,dy)),  \
                               __fmul_rn(dz,dz));                              \
    const u64 kv = ((u64)__float_as_uint(__fsqrt_rn(sq)) << 13) | (u32)(i);

// tanh via hardware exp/rcp: tanh(y) = 1 - 2/(1+e^{2y}); saturates correctly.
__device__ __forceinline__ float tanh_fast(float y) {
    const float e = __expf(2.0f * y);
    const float r = __builtin_amdgcn_rcpf(e + 1.0f);
    return fmaf(-2.0f, r, 1.0f);
}

__device__ __forceinline__ short bf_bits(float f) {
    const __hip_bfloat16 h = __float2bfloat16(f);   // RNE
    short s;
    __builtin_memcpy(&s, &h, 2);
    return s;
}

__device__ __forceinline__ int mbcnt64(u64 m) {
    return (int)__builtin_amdgcn_mbcnt_hi((u32)(m >> 32),
           __builtin_amdgcn_mbcnt_lo((u32)m, 0u));
}

// ======= Kernel 1: fused prep (blocks 0..511) + KNN (256 threads, proven) =======
__global__ __launch_bounds__(256, 8)
void knn_kernel(const float* __restrict__ pos,     // (B,N,3)
                const int*   __restrict__ snidx,   // (S,)
                const float* __restrict__ w1,      // (HID,HID)
                const float* __restrict__ w2,      // (HID,HID)
                __hip_bfloat16* __restrict__ wf,   // frag-packed weights out
                int*         __restrict__ nbr_g)   // (B*S, KK)
{
    if (blockIdx.x < PREPB) {
        // ---- prep: split w1/w2 into bf16 hi+lo, MFMA B-frag order ----
        const int idx = blockIdx.x * 256 + threadIdx.x;   // 0..131071
        const int j   = idx & 7;
        const int l   = (idx >> 3) & 63;
        const int ntg = (idx >> 9) & 15;
        const int ks  = (idx >> 13) & 7;
        const int mat = idx >> 16;
        const int k = ks * 32 + (l >> 4) * 8 + j;
        const int n = ntg * 16 + (l & 15);
        const float v = (mat ? w2 : w1)[k * HID + n];
        const __hip_bfloat16 hi = __float2bfloat16(v);
        const float res = v - __bfloat162float(hi);
        const size_t sl = (size_t)mat * 131072 + ((size_t)((ks*16 + ntg)*2) * 64 + l) * 8 + j;
        wf[sl]       = hi;
        wf[sl + 512] = __float2bfloat16(res);            // hl=1 slot
        return;
    }

    const int bs   = blockIdx.x - PREPB;    // 0 .. B*S-1
    const int b    = bs / SS;
    const int s    = bs - b * SS;
    const int t    = threadIdx.x;
    const int lane = t & 63;
    const int wv   = t >> 6;

    __shared__ u64 wl[4 * KK];          // 4 waves x 32 selected keys

    const float* posb = pos + (size_t)b * (NN * 3);
    const int   sp = snidx[s];
    const float sx = posb[sp*3 + 0];
    const float sy = posb[sp*3 + 1];
    const float sz = posb[sp*3 + 2];

    // ---- Phase 1: stream distances, per-lane sorted top-5 (depth-5) ----
    u64 s0=SENT,s1=SENT,s2=SENT,s3=SENT,s4=SENT,s5=SENT,s6=SENT,s7=SENT;
#pragma unroll 4
    for (int c = 0; c < 32; ++c) {
        const int i = c * 256 + t;
        DIST_KEY(i, kv)
        INS5(kv);
    }

#define CNT5(CAND) (__popcll(__ballot(s0<(CAND)))+__popcll(__ballot(s1<(CAND))) \
                   +__popcll(__ballot(s2<(CAND)))+__popcll(__ballot(s3<(CAND))) \
                   +__popcll(__ballot(s4<(CAND))))
#define CNT8(CAND) (CNT5(CAND)+__popcll(__ballot(s5<(CAND))) \
                   +__popcll(__ballot(s6<(CAND)))+__popcll(__ballot(s7<(CAND))))

    // ---- Phase 2: wave threshold selection (ballot binary search, depth-5) ----
    {
        u64 L = 0;
        for (int bit = 43; bit >= 13; --bit) {
            const u64 cand = L | (1ull << bit);
            if (CNT5(cand) < 32) L = cand;
        }
        u64 TH = L + (1ull << 13);
        if (CNT5(TH) != 32) {                      // distbit tie: resolve by idx
            for (int bit = 12; bit >= 0; --bit) {
                const u64 cand = L | (1ull << bit);
                if (CNT5(cand) < 32) L = cand;
            }
            TH = L + 1;
        }
        bool b0 = s0 < TH, b1 = s1 < TH, b2 = s2 < TH, b3 = s3 < TH, b4 = s4 < TH;
        bool b5 = false, b6 = false, b7 = false;
        const int csel5 = (int)b0+(int)b1+(int)b2+(int)b3+(int)b4;
        bool need_serial = false;

        if (__ballot(csel5 == 5) != 0ull) {
            // Tier 2 (P~1%/wave): extend all lanes to verified depth-8, redo.
            s5 = s6 = s7 = SENT;
#pragma unroll 4
            for (int c = 0; c < 32; ++c) {
                const int i = c * 256 + t;
                DIST_KEY(i, kv)
                const u64 kf = kv > s4 ? kv : SENT;
                INS3HI(kf);
            }
            u64 L8 = 0;
            for (int bit = 43; bit >= 13; --bit) {
                const u64 cand = L8 | (1ull << bit);
                if (CNT8(cand) < 32) L8 = cand;
            }
            u64 TH8 = L8 + (1ull << 13);
            if (CNT8(TH8) != 32) {
                for (int bit = 12; bit >= 0; --bit) {
                    const u64 cand = L8 | (1ull << bit);
                    if (CNT8(cand) < 32) L8 = cand;
                }
                TH8 = L8 + 1;
            }
            b0 = s0 < TH8; b1 = s1 < TH8; b2 = s2 < TH8; b3 = s3 < TH8;
            b4 = s4 < TH8; b5 = s5 < TH8; b6 = s6 < TH8; b7 = s7 < TH8;
            const int csel8 = (int)b0+(int)b1+(int)b2+(int)b3
                            + (int)b4+(int)b5+(int)b6+(int)b7;
            need_serial = __ballot(csel8 == 8) != 0ull;
        }

        if (need_serial) {
            // Tier 3 (P~1e-3/launch): proven serial extraction, depth-8 buffer.
            int nv = (int)(s0!=SENT)+(int)(s1!=SENT)+(int)(s2!=SENT)+(int)(s3!=SENT)
                   + (int)(s4!=SENT)+(int)(s5!=SENT)+(int)(s6!=SENT)+(int)(s7!=SENT);
#pragma unroll 1
            for (int it = 0; it < KK; ++it) {
                u64 m = s0;
#pragma unroll
                for (int off = 32; off > 0; off >>= 1) {
                    const u64 o = __shfl_xor(m, off, 64);
                    m = o < m ? o : m;
                }
                if (lane == 0) wl[wv*KK + it] = m;
                if (s0 == m) {
                    s0=s1; s1=s2; s2=s3; s3=s4; s4=s5; s5=s6; s6=s7; s7=SENT;
                    if (--nv == 0) {
                        const u64 last = m;
                        s0=s1=s2=s3=s4=s5=s6=s7=SENT;
#pragma unroll 4
                        for (int c = 0; c < 32; ++c) {
                            const int i = c * 256 + t;
                            DIST_KEY(i, kv)
                            const u64 kf = kv > last ? kv : SENT;
                            INS8(kf);
                        }
                        nv = (int)(s0!=SENT)+(int)(s1!=SENT)+(int)(s2!=SENT)+(int)(s3!=SENT)
                           + (int)(s4!=SENT)+(int)(s5!=SENT)+(int)(s6!=SENT)+(int)(s7!=SENT);
                    }
                }
            }
        } else {
            // Compaction (order irrelevant downstream; output is a mean over k).
            const u64 m0=__ballot(b0), m1=__ballot(b1), m2=__ballot(b2), m3=__ballot(b3),
                      m4=__ballot(b4), m5=__ballot(b5), m6=__ballot(b6), m7=__ballot(b7);
            int p = mbcnt64(m0)+mbcnt64(m1)+mbcnt64(m2)+mbcnt64(m3)
                  + mbcnt64(m4)+mbcnt64(m5)+mbcnt64(m6)+mbcnt64(m7);
            u64* wwl = &wl[wv * KK];
            if (b0) { wwl[p] = s0; ++p; }
            if (b1) { wwl[p] = s1; ++p; }
            if (b2) { wwl[p] = s2; ++p; }
            if (b3) { wwl[p] = s3; ++p; }
            if (b4) { wwl[p] = s4; ++p; }
            if (b5) { wwl[p] = s5; ++p; }
            if (b6) { wwl[p] = s6; ++p; }
            if (b7) { wwl[p] = s7; }
        }
    }
    __syncthreads();

    // ---- Phase 2b: block stage — top-32 of the 128 wave-selected keys ----
    if (t < 64) {
        const u64 k0 = wl[lane], k1 = wl[64 + lane];
        u64 L = 0;
        for (int bit = 43; bit >= 13; --bit) {
            const u64 cand = L | (1ull << bit);
            const int cnt = __popcll(__ballot(k0 < cand)) + __popcll(__ballot(k1 < cand));
            if (cnt < 32) L = cand;
        }
        u64 TH = L + (1ull << 13);
        {
            const int cnt = __popcll(__ballot(k0 < TH)) + __popcll(__ballot(k1 < TH));
            if (cnt != 32) {
                for (int bit = 12; bit >= 0; --bit) {
                    const u64 cand = L | (1ull << bit);
                    const int c2 = __popcll(__ballot(k0 < cand)) + __popcll(__ballot(k1 < cand));
                    if (c2 < 32) L = cand;
                }
                TH = L + 1;
            }
        }
        const bool c0 = k0 < TH, c1 = k1 < TH;
        const int p = mbcnt64(__ballot(c0)) + mbcnt64(__ballot(c1));
        if (c0) nbr_g[(size_t)bs * KK + p]           = (int)(k0 & 8191u);
        if (c1) nbr_g[(size_t)bs * KK + p + (int)c0] = (int)(k1 & 8191u);
    }
}

// ==== Kernel 2: embed + MLP (M=96, 3 tokens, 512 threads, 3 blocks/CU) ====
__global__ __launch_bounds__(512, 4)
void mlp_kernel(const float* __restrict__ pos,     // (B,N,3)
                const int*   __restrict__ nbr_g,   // (B*S, KK)
                const float* __restrict__ w_in,    // (3,HID)
                const float* __restrict__ b_in,    // (HID,)
                const float* __restrict__ b1,      // (HID,)
                const float* __restrict__ b2,      // (HID,)
                const __hip_bfloat16* __restrict__ wf,
                float*       __restrict__ out)     // (B,S,HID)
{
    const int tk0  = blockIdx.x * MT;   // first of up to 3 tokens (may span batches)
    const int cnt  = (NTOK - tk0) < MT ? (NTOK - tk0) : MT;
    const int t    = threadIdx.x;
    const int lane = t & 63;
    const int wv   = t >> 6;            // 0..7

    __shared__ __align__(16) short h0b[MT * KK][LDB]; // 96 rows (50688 B)
    __shared__ __align__(16) float nbc[MT * 4 * KK];  // float4-strided coords

    // ---- gather neighbor coords (per-token batch; guarded vs OOB) ----
    if (t < MT * KK * 3) {
        const int k = t / 3, d = t - 3 * k;        // row k in [0,96)
        if (k < cnt * KK) {
            const int tk = tk0 + k / KK;           // this row's token
            const int bq = tk / SS;                // its batch
            const int idx = nbr_g[(size_t)tk * KK + (k & (KK-1))];
            nbc[k * 4 + d] = pos[(size_t)bq * (NN * 3) + (size_t)idx * 3 + d];
        }
    }
    __syncthreads();

    // ---- h0 = coords @ w_in + b_in + sincos PE -> bf16 ----
    // thread = (channel c = t&255, half = t>>8); each computes 48 rows.
    // Rows >= cnt*32 read stale nbc -> garbage values, discarded in epilogue.
    {
        const int  c     = t & 255;
        const int  kh    = (t >> 8) * 48;           // 0 or 48
        const int  dimi  = c / 84;                  // 84 = 2*42 channels per dim
        const int  cc    = c - dimi * 84;
        const bool hasPe = c < 252;
        const bool isCos = cc >= 42;
        const int  f     = isCos ? cc - 42 : cc;
        const float fcoef = (float)(-9.210340371976184 / 41.0);
        const float freqv = expf((float)f * fcoef);
        const int  di    = hasPe ? dimi : 0;

        const float wi0 = w_in[0*HID + c];
        const float wi1 = w_in[1*HID + c];
        const float wi2 = w_in[2*HID + c];
        const float bi  = b_in[c];

#pragma unroll 4
        for (int kk = 0; kk < 48; ++kk) {
            const int k = kh + kk;
            const float4 xv4 = *(const float4*)&nbc[k * 4];   // one b128 read
            const float x0 = xv4.x, x1 = xv4.y, x2 = xv4.z;
            float v = fmaf(x2, wi2, fmaf(x1, wi1, fmaf(x0, wi0, bi)));
            if (hasPe) {
                const float xv  = (di == 0) ? x0 : ((di == 1) ? x1 : x2);
                const float ang = xv * freqv;
                v += isCos ? __cosf(ang) : __sinf(ang);   // native (args |x|<~6)
            }
            h0b[k][c] = bf_bits(v);
        }
    }
    __syncthreads();

    // ---- MLP via bf16 MFMA, split weights (hi+lo); M=96, wave owns 32 channels ----
    // A frag (16x16x32): row = lane&15, k = ks*32 + (lane>>4)*8 + j  (matches prep).
    // C/D: col = lane&15, row = (lane>>4)*4 + reg   [HW-verified m89]
    const int lr = lane & 15;
    const int lg = lane >> 4;
    const int nbase = wv * 32;                     // ntg = wv*2 + nt

    const short* arow[6];
#pragma unroll
    for (int mt = 0; mt < 6; ++mt) arow[mt] = &h0b[mt * 16 + lr][lg * 8];
    // weight slot = mat*131072 + ks*16384 + ntg*1024 + hl*512 + lane*8
    const __hip_bfloat16* wb1 = wf + (size_t)wv * 2048 + lane * 8;
    const __hip_bfloat16* wb2 = wb1 + 2 * WFE;

    f32x4 acc[6][2];

    // ---- layer 1: h1 = h0 @ w1 + b1 ----
    {
#pragma unroll
        for (int nt = 0; nt < 2; ++nt) {
            const float bias = b1[nbase + nt*16 + lr];
            const f32x4 bv = {bias, bias, bias, bias};
#pragma unroll
            for (int mt = 0; mt < 6; ++mt) acc[mt][nt] = bv;
        }
#pragma unroll 1
        for (int ks = 0; ks < 8; ++ks) {
            bf16x8 af[6];
#pragma unroll
            for (int mt = 0; mt < 6; ++mt) af[mt] = *(const bf16x8*)(arow[mt] + ks * 32);
            const __hip_bfloat16* p = wb1 + ks * 16384;
#pragma unroll
            for (int nt = 0; nt < 2; ++nt) {
                const bf16x8 bh = *(const bf16x8*)(p + nt * 1024);
#pragma unroll
                for (int mt = 0; mt < 6; ++mt)
                    acc[mt][nt] = __builtin_amdgcn_mfma_f32_16x16x32_bf16(af[mt], bh, acc[mt][nt], 0,0,0);
                const bf16x8 bl = *(const bf16x8*)(p + nt * 1024 + 512);
#pragma unroll
                for (int mt = 0; mt < 6; ++mt)
                    acc[mt][nt] = __builtin_amdgcn_mfma_f32_16x16x32_bf16(af[mt], bl, acc[mt][nt], 0,0,0);
            }
        }
    }
    __syncthreads();                                 // all layer-1 h0 reads done

    // gelu (tanh approx) -> h0b (bf16; same rounding as before)
    {
        const float kA = 0.7978845608028654f;        // sqrt(2/pi)
#pragma unroll
        for (int mt = 0; mt < 6; ++mt)
#pragma unroll
        for (int nt = 0; nt < 2; ++nt)
#pragma unroll
        for (int r = 0; r < 4; ++r) {
            const float x  = acc[mt][nt][r];
            const float x3 = x * x * x;
            const float tv = tanh_fast(kA * fmaf(0.044715f, x3, x));
            h0b[mt*16 + lg*4 + r][nbase + nt*16 + lr] = bf_bits(0.5f * x * (1.0f + tv));
        }
    }
    __syncthreads();

    // ---- layer 2: g @ w2 (bias+mean folded into epilogue) ----
    {
        const f32x4 z = {0.f, 0.f, 0.f, 0.f};
#pragma unroll
        for (int nt = 0; nt < 2; ++nt)
#pragma unroll
            for (int mt = 0; mt < 6; ++mt) acc[mt][nt] = z;
#pragma unroll 1
        for (int ks = 0; ks < 8; ++ks) {
            bf16x8 af[6];
#pragma unroll
            for (int mt = 0; mt < 6; ++mt) af[mt] = *(const bf16x8*)(arow[mt] + ks * 32);
            const __hip_bfloat16* p = wb2 + ks * 16384;
#pragma unroll
            for (int nt = 0; nt < 2; ++nt) {
                const bf16x8 bh = *(const bf16x8*)(p + nt * 1024);
#pragma unroll
                for (int mt = 0; mt < 6; ++mt)
                    acc[mt][nt] = __builtin_amdgcn_mfma_f32_16x16x32_bf16(af[mt], bh, acc[mt][nt], 0,0,0);
                const bf16x8 bl = *(const bf16x8*)(p + nt * 1024 + 512);
#pragma unroll
                for (int mt = 0; mt < 6; ++mt)
                    acc[mt][nt] = __builtin_amdgcn_mfma_f32_16x16x32_bf16(af[mt], bl, acc[mt][nt], 0,0,0);
            }
        }
    }

    // ---- epilogue: per-token mean over 32 rows + b2; lanes<16 write ----
#pragma unroll
    for (int nt = 0; nt < 2; ++nt) {
        float sums[MT];
#pragma unroll
        for (int q = 0; q < MT; ++q) {
            float sv = 0.0f;
#pragma unroll
            for (int r = 0; r < 4; ++r)
                sv += acc[2*q][nt][r] + acc[2*q + 1][nt][r];
            sv += __shfl_xor(sv, 16, 64);
            sv += __shfl_xor(sv, 32, 64);
            sums[q] = sv;
        }
        if (lane < 16) {
            const int ch = nbase + nt*16 + lane;
            const float bb = b2[ch];
#pragma unroll
            for (int q = 0; q < MT; ++q)
                if (q < cnt)
                    out[(size_t)(tk0 + q) * HID + ch] = fmaf(sums[q], 1.0f / KK, bb);
        }
    }
}

extern "C" void kernel_launch(void* const* d_in, const int* in_sizes, int n_in,
                              void* d_out, int out_size, void* d_ws, size_t ws_size,
                              hipStream_t stream) {
    const float* pos  = (const float*)d_in[0];
    const int*   sni  = (const int*)  d_in[1];
    const float* w_in = (const float*)d_in[2];
    const float* b_in = (const float*)d_in[3];
    const float* w1   = (const float*)d_in[4];
    const float* b1   = (const float*)d_in[5];
    const float* w2   = (const float*)d_in[6];
    const float* b2   = (const float*)d_in[7];
    float* out = (float*)d_out;
    __hip_bfloat16* wf = (__hip_bfloat16*)d_ws;            // 512 KB
    int* nbr_g = (int*)((char*)d_ws + 4 * WFE * 2);        // +256 KB
    (void)in_sizes; (void)n_in; (void)out_size; (void)ws_size;

    hipLaunchKernelGGL(knn_kernel, dim3(PREPB + NTOK), dim3(256), 0, stream,
                       pos, sni, w1, w2, wf, nbr_g);
    hipLaunchKernelGGL(mlp_kernel, dim3((NTOK + MT - 1) / MT), dim3(512), 0, stream,
                       pos, nbr_g, w_in, b_in, b1, b2, wf, out);
}

// Round 22
// 72.347 us; speedup vs baseline: 1.0667x; 1.0667x over previous
//
#include <hip/hip_runtime.h>
#include <hip/hip_bf16.h>
#include <math.h>

#define BB   2
#define NN   8192
#define SS   1024
#define KK   32
#define HID  256
#define SENT 0xFFFFFFFFFFFFFFFFULL
#define LDB  264       // padded LDS row stride (bf16 elems)
#define WFE  65536     // frag elements per matrix copy (256*256)
#define PREPB 512      // prep blocks (256 thr each) fused ahead of knn grid

typedef unsigned long long u64;
typedef unsigned int       u32;
typedef short bf16x8 __attribute__((ext_vector_type(8)));
typedef float f32x4  __attribute__((ext_vector_type(4)));

// compare-swap carry chain step
#define CSW(SI) { const u64 mn = x < (SI) ? x : (SI); const u64 mx = x < (SI) ? (SI) : x; (SI) = mn; x = mx; }
#define INS5(KV) { u64 x = (KV); CSW(s0) CSW(s1) CSW(s2) CSW(s3) CSW(s4) }
#define INS3HI(KV) { u64 x = (KV); CSW(s5) CSW(s6) CSW(s7) }
#define INS8(KV) { u64 x = (KV); CSW(s0) CSW(s1) CSW(s2) CSW(s3) CSW(s4) CSW(s5) CSW(s6) CSW(s7) }

#define DIST_KEY(i, kv)                                                        \
    const float dx = __fsub_rn(sx, posb[(i)*3 + 0]);                           \
    const float dy = __fsub_rn(sy, posb[(i)*3 + 1]);                           \
    const float dz = __fsub_rn(sz, posb[(i)*3 + 2]);                           \
    const float sq = __fadd_rn(__fadd_rn(__fmul_rn(dx,dx), __fmul_rn(dy,dy)),  \
                               __fmul_rn(dz,dz));                              \
    const u64 kv = ((u64)__float_as_uint(__fsqrt_rn(sq)) << 13) | (u32)(i);

// tanh via hardware exp/rcp: tanh(y) = 1 - 2/(1+e^{2y}); saturates correctly.
__device__ __forceinline__ float tanh_fast(float y) {
    const float e = __expf(2.0f * y);
    const float r = __builtin_amdgcn_rcpf(e + 1.0f);
    return fmaf(-2.0f, r, 1.0f);
}

__device__ __forceinline__ short bf_bits(float f) {
    const __hip_bfloat16 h = __float2bfloat16(f);   // RNE
    short s;
    __builtin_memcpy(&s, &h, 2);
    return s;
}

__device__ __forceinline__ int mbcnt64(u64 m) {
    return (int)__builtin_amdgcn_mbcnt_hi((u32)(m >> 32),
           __builtin_amdgcn_mbcnt_lo((u32)m, 0u));
}

// ======= Kernel 1: fused prep (blocks 0..511) + KNN (256 threads, proven) =======
__global__ __launch_bounds__(256, 8)
void knn_kernel(const float* __restrict__ pos,     // (B,N,3)
                const int*   __restrict__ snidx,   // (S,)
                const float* __restrict__ w1,      // (HID,HID)
                const float* __restrict__ w2,      // (HID,HID)
                __hip_bfloat16* __restrict__ wf,   // frag-packed weights out
                int*         __restrict__ nbr_g)   // (B*S, KK)
{
    if (blockIdx.x < PREPB) {
        // ---- prep: split w1/w2 into bf16 hi+lo, MFMA B-frag order ----
        const int idx = blockIdx.x * 256 + threadIdx.x;   // 0..131071
        const int j   = idx & 7;
        const int l   = (idx >> 3) & 63;
        const int ntg = (idx >> 9) & 15;
        const int ks  = (idx >> 13) & 7;
        const int mat = idx >> 16;
        const int k = ks * 32 + (l >> 4) * 8 + j;
        const int n = ntg * 16 + (l & 15);
        const float v = (mat ? w2 : w1)[k * HID + n];
        const __hip_bfloat16 hi = __float2bfloat16(v);
        const float res = v - __bfloat162float(hi);
        const size_t sl = (size_t)mat * 131072 + ((size_t)((ks*16 + ntg)*2) * 64 + l) * 8 + j;
        wf[sl]       = hi;
        wf[sl + 512] = __float2bfloat16(res);            // hl=1 slot
        return;
    }

    const int bs   = blockIdx.x - PREPB;    // 0 .. B*S-1
    const int b    = bs / SS;
    const int s    = bs - b * SS;
    const int t    = threadIdx.x;
    const int lane = t & 63;
    const int wv   = t >> 6;

    __shared__ u64 wl[4 * KK];          // 4 waves x 32 selected keys

    const float* posb = pos + (size_t)b * (NN * 3);
    const int   sp = snidx[s];
    const float sx = posb[sp*3 + 0];
    const float sy = posb[sp*3 + 1];
    const float sz = posb[sp*3 + 2];

    // ---- Phase 1: stream distances, per-lane sorted top-5 (depth-5) ----
    u64 s0=SENT,s1=SENT,s2=SENT,s3=SENT,s4=SENT,s5=SENT,s6=SENT,s7=SENT;
#pragma unroll 4
    for (int c = 0; c < 32; ++c) {
        const int i = c * 256 + t;
        DIST_KEY(i, kv)
        INS5(kv);
    }

#define CNT5(CAND) (__popcll(__ballot(s0<(CAND)))+__popcll(__ballot(s1<(CAND))) \
                   +__popcll(__ballot(s2<(CAND)))+__popcll(__ballot(s3<(CAND))) \
                   +__popcll(__ballot(s4<(CAND))))
#define CNT8(CAND) (CNT5(CAND)+__popcll(__ballot(s5<(CAND))) \
                   +__popcll(__ballot(s6<(CAND)))+__popcll(__ballot(s7<(CAND))))

    // ---- Phase 2: wave threshold selection (ballot binary search, depth-5) ----
    {
        u64 L = 0;
        for (int bit = 43; bit >= 13; --bit) {
            const u64 cand = L | (1ull << bit);
            if (CNT5(cand) < 32) L = cand;
        }
        u64 TH = L + (1ull << 13);
        if (CNT5(TH) != 32) {                      // distbit tie: resolve by idx
            for (int bit = 12; bit >= 0; --bit) {
                const u64 cand = L | (1ull << bit);
                if (CNT5(cand) < 32) L = cand;
            }
            TH = L + 1;
        }
        bool b0 = s0 < TH, b1 = s1 < TH, b2 = s2 < TH, b3 = s3 < TH, b4 = s4 < TH;
        bool b5 = false, b6 = false, b7 = false;
        const int csel5 = (int)b0+(int)b1+(int)b2+(int)b3+(int)b4;
        bool need_serial = false;

        if (__ballot(csel5 == 5) != 0ull) {
            // Tier 2 (P~1%/wave): extend all lanes to verified depth-8, redo.
            s5 = s6 = s7 = SENT;
#pragma unroll 4
            for (int c = 0; c < 32; ++c) {
                const int i = c * 256 + t;
                DIST_KEY(i, kv)
                const u64 kf = kv > s4 ? kv : SENT;
                INS3HI(kf);
            }
            u64 L8 = 0;
            for (int bit = 43; bit >= 13; --bit) {
                const u64 cand = L8 | (1ull << bit);
                if (CNT8(cand) < 32) L8 = cand;
            }
            u64 TH8 = L8 + (1ull << 13);
            if (CNT8(TH8) != 32) {
                for (int bit = 12; bit >= 0; --bit) {
                    const u64 cand = L8 | (1ull << bit);
                    if (CNT8(cand) < 32) L8 = cand;
                }
                TH8 = L8 + 1;
            }
            b0 = s0 < TH8; b1 = s1 < TH8; b2 = s2 < TH8; b3 = s3 < TH8;
            b4 = s4 < TH8; b5 = s5 < TH8; b6 = s6 < TH8; b7 = s7 < TH8;
            const int csel8 = (int)b0+(int)b1+(int)b2+(int)b3
                            + (int)b4+(int)b5+(int)b6+(int)b7;
            need_serial = __ballot(csel8 == 8) != 0ull;
        }

        if (need_serial) {
            // Tier 3 (P~1e-3/launch): proven serial extraction, depth-8 buffer.
            int nv = (int)(s0!=SENT)+(int)(s1!=SENT)+(int)(s2!=SENT)+(int)(s3!=SENT)
                   + (int)(s4!=SENT)+(int)(s5!=SENT)+(int)(s6!=SENT)+(int)(s7!=SENT);
#pragma unroll 1
            for (int it = 0; it < KK; ++it) {
                u64 m = s0;
#pragma unroll
                for (int off = 32; off > 0; off >>= 1) {
                    const u64 o = __shfl_xor(m, off, 64);
                    m = o < m ? o : m;
                }
                if (lane == 0) wl[wv*KK + it] = m;
                if (s0 == m) {
                    s0=s1; s1=s2; s2=s3; s3=s4; s4=s5; s5=s6; s6=s7; s7=SENT;
                    if (--nv == 0) {
                        const u64 last = m;
                        s0=s1=s2=s3=s4=s5=s6=s7=SENT;
#pragma unroll 4
                        for (int c = 0; c < 32; ++c) {
                            const int i = c * 256 + t;
                            DIST_KEY(i, kv)
                            const u64 kf = kv > last ? kv : SENT;
                            INS8(kf);
                        }
                        nv = (int)(s0!=SENT)+(int)(s1!=SENT)+(int)(s2!=SENT)+(int)(s3!=SENT)
                           + (int)(s4!=SENT)+(int)(s5!=SENT)+(int)(s6!=SENT)+(int)(s7!=SENT);
                    }
                }
            }
        } else {
            // Compaction (order irrelevant downstream; output is a mean over k).
            const u64 m0=__ballot(b0), m1=__ballot(b1), m2=__ballot(b2), m3=__ballot(b3),
                      m4=__ballot(b4), m5=__ballot(b5), m6=__ballot(b6), m7=__ballot(b7);
            int p = mbcnt64(m0)+mbcnt64(m1)+mbcnt64(m2)+mbcnt64(m3)
                  + mbcnt64(m4)+mbcnt64(m5)+mbcnt64(m6)+mbcnt64(m7);
            u64* wwl = &wl[wv * KK];
            if (b0) { wwl[p] = s0; ++p; }
            if (b1) { wwl[p] = s1; ++p; }
            if (b2) { wwl[p] = s2; ++p; }
            if (b3) { wwl[p] = s3; ++p; }
            if (b4) { wwl[p] = s4; ++p; }
            if (b5) { wwl[p] = s5; ++p; }
            if (b6) { wwl[p] = s6; ++p; }
            if (b7) { wwl[p] = s7; }
        }
    }
    __syncthreads();

    // ---- Phase 2b: block stage — top-32 of the 128 wave-selected keys ----
    if (t < 64) {
        const u64 k0 = wl[lane], k1 = wl[64 + lane];
        u64 L = 0;
        for (int bit = 43; bit >= 13; --bit) {
            const u64 cand = L | (1ull << bit);
            const int cnt = __popcll(__ballot(k0 < cand)) + __popcll(__ballot(k1 < cand));
            if (cnt < 32) L = cand;
        }
        u64 TH = L + (1ull << 13);
        {
            const int cnt = __popcll(__ballot(k0 < TH)) + __popcll(__ballot(k1 < TH));
            if (cnt != 32) {
                for (int bit = 12; bit >= 0; --bit) {
                    const u64 cand = L | (1ull << bit);
                    const int c2 = __popcll(__ballot(k0 < cand)) + __popcll(__ballot(k1 < cand));
                    if (c2 < 32) L = cand;
                }
                TH = L + 1;
            }
        }
        const bool c0 = k0 < TH, c1 = k1 < TH;
        const int p = mbcnt64(__ballot(c0)) + mbcnt64(__ballot(c1));
        if (c0) nbr_g[(size_t)bs * KK + p]           = (int)(k0 & 8191u);
        if (c1) nbr_g[(size_t)bs * KK + p + (int)c0] = (int)(k1 & 8191u);
    }
}

// ==== Kernel 2: embed + MLP (M=128, 4 tokens, 512 threads, (512,4)) ====
__global__ __launch_bounds__(512, 4)
void mlp_kernel(const float* __restrict__ pos,     // (B,N,3)
                const int*   __restrict__ nbr_g,   // (B*S, KK)
                const float* __restrict__ w_in,    // (3,HID)
                const float* __restrict__ b_in,    // (HID,)
                const float* __restrict__ b1,      // (HID,)
                const float* __restrict__ b2,      // (HID,)
                const __hip_bfloat16* __restrict__ wf,
                float*       __restrict__ out)     // (B,S,HID)
{
    const int tk0  = blockIdx.x * 4;    // first of 4 tokens, all same b (1024%4==0)
    const int b    = tk0 / SS;
    const int t    = threadIdx.x;
    const int lane = t & 63;
    const int wv   = t >> 6;            // 0..7

    __shared__ __align__(16) short h0b[4 * KK][LDB]; // 128 rows (67584 B)
    __shared__ __align__(16) float nbc[4 * 4 * KK];  // float4-strided coords

    const float* posb = pos + (size_t)b * (NN * 3);

    // ---- gather neighbor coords (float4-strided for b128 reads) ----
    if (t < 4 * KK * 3) {
        const int k = t / 3, d = t - 3 * k;        // k in [0,128)
        nbc[k * 4 + d] = posb[(size_t)nbr_g[(size_t)tk0 * KK + k] * 3 + d];
    }
    __syncthreads();

    // ---- h0 = coords @ w_in + b_in + sincos PE -> bf16 ----
    // thread = (channel c = t&255, half = t>>8); each computes 64 rows.
    {
        const int  c     = t & 255;
        const int  kh    = (t >> 8) * 64;           // 0 or 64
        const int  dimi  = c / 84;                  // 84 = 2*42 channels per dim
        const int  cc    = c - dimi * 84;
        const bool hasPe = c < 252;
        const bool isCos = cc >= 42;
        const int  f     = isCos ? cc - 42 : cc;
        const float fcoef = (float)(-9.210340371976184 / 41.0);
        const float freqv = expf((float)f * fcoef);
        const int  di    = hasPe ? dimi : 0;

        const float wi0 = w_in[0*HID + c];
        const float wi1 = w_in[1*HID + c];
        const float wi2 = w_in[2*HID + c];
        const float bi  = b_in[c];

#pragma unroll 4
        for (int kk = 0; kk < 64; ++kk) {
            const int k = kh + kk;
            const float4 xv4 = *(const float4*)&nbc[k * 4];   // one b128 read
            const float x0 = xv4.x, x1 = xv4.y, x2 = xv4.z;
            float v = fmaf(x2, wi2, fmaf(x1, wi1, fmaf(x0, wi0, bi)));
            if (hasPe) {
                const float xv  = (di == 0) ? x0 : ((di == 1) ? x1 : x2);
                const float ang = xv * freqv;
                v += isCos ? __cosf(ang) : __sinf(ang);   // native (args |x|<~6)
            }
            h0b[k][c] = bf_bits(v);
        }
    }
    __syncthreads();

    // ---- MLP via bf16 MFMA, split weights (hi+lo); M=128, wave owns 32 channels ----
    // A frag (16x16x32): row = lane&15, k = ks*32 + (lane>>4)*8 + j  (matches prep).
    // C/D: col = lane&15, row = (lane>>4)*4 + reg   [HW-verified m89]
    const int lr = lane & 15;
    const int lg = lane >> 4;
    const int nbase = wv * 32;                     // ntg = wv*2 + nt

    const short* arow[8];
#pragma unroll
    for (int mt = 0; mt < 8; ++mt) arow[mt] = &h0b[mt * 16 + lr][lg * 8];
    // weight slot = mat*131072 + ks*16384 + ntg*1024 + hl*512 + lane*8
    const __hip_bfloat16* wb1 = wf + (size_t)wv * 2048 + lane * 8;
    const __hip_bfloat16* wb2 = wb1 + 2 * WFE;

    f32x4 acc[8][2];

    // ---- layer 1: h1 = h0 @ w1 + b1 ----
    {
#pragma unroll
        for (int nt = 0; nt < 2; ++nt) {
            const float bias = b1[nbase + nt*16 + lr];
            const f32x4 bv = {bias, bias, bias, bias};
#pragma unroll
            for (int mt = 0; mt < 8; ++mt) acc[mt][nt] = bv;
        }
#pragma unroll 1
        for (int ks = 0; ks < 8; ++ks) {
            bf16x8 af[8];
#pragma unroll
            for (int mt = 0; mt < 8; ++mt) af[mt] = *(const bf16x8*)(arow[mt] + ks * 32);
            const __hip_bfloat16* p = wb1 + ks * 16384;
#pragma unroll
            for (int nt = 0; nt < 2; ++nt) {
                const bf16x8 bh = *(const bf16x8*)(p + nt * 1024);
#pragma unroll
                for (int mt = 0; mt < 8; ++mt)
                    acc[mt][nt] = __builtin_amdgcn_mfma_f32_16x16x32_bf16(af[mt], bh, acc[mt][nt], 0,0,0);
                const bf16x8 bl = *(const bf16x8*)(p + nt * 1024 + 512);
#pragma unroll
                for (int mt = 0; mt < 8; ++mt)
                    acc[mt][nt] = __builtin_amdgcn_mfma_f32_16x16x32_bf16(af[mt], bl, acc[mt][nt], 0,0,0);
            }
        }
    }
    __syncthreads();                                 // all layer-1 h0 reads done

    // gelu (tanh approx) -> h0b (bf16; same rounding as before)
    {
        const float kA = 0.7978845608028654f;        // sqrt(2/pi)
#pragma unroll
        for (int mt = 0; mt < 8; ++mt)
#pragma unroll
        for (int nt = 0; nt < 2; ++nt)
#pragma unroll
        for (int r = 0; r < 4; ++r) {
            const float x  = acc[mt][nt][r];
            const float x3 = x * x * x;
            const float tv = tanh_fast(kA * fmaf(0.044715f, x3, x));
            h0b[mt*16 + lg*4 + r][nbase + nt*16 + lr] = bf_bits(0.5f * x * (1.0f + tv));
        }
    }
    __syncthreads();

    // ---- layer 2: g @ w2 (bias+mean folded into epilogue) ----
    {
        const f32x4 z = {0.f, 0.f, 0.f, 0.f};
#pragma unroll
        for (int nt = 0; nt < 2; ++nt)
#pragma unroll
            for (int mt = 0; mt < 8; ++mt) acc[mt][nt] = z;
#pragma unroll 1
        for (int ks = 0; ks < 8; ++ks) {
            bf16x8 af[8];
#pragma unroll
            for (int mt = 0; mt < 8; ++mt) af[mt] = *(const bf16x8*)(arow[mt] + ks * 32);
            const __hip_bfloat16* p = wb2 + ks * 16384;
#pragma unroll
            for (int nt = 0; nt < 2; ++nt) {
                const bf16x8 bh = *(const bf16x8*)(p + nt * 1024);
#pragma unroll
                for (int mt = 0; mt < 8; ++mt)
                    acc[mt][nt] = __builtin_amdgcn_mfma_f32_16x16x32_bf16(af[mt], bh, acc[mt][nt], 0,0,0);
                const bf16x8 bl = *(const bf16x8*)(p + nt * 1024 + 512);
#pragma unroll
                for (int mt = 0; mt < 8; ++mt)
                    acc[mt][nt] = __builtin_amdgcn_mfma_f32_16x16x32_bf16(af[mt], bl, acc[mt][nt], 0,0,0);
            }
        }
    }

    // ---- epilogue: per-token mean over 32 rows + b2; lanes<16 write ----
#pragma unroll
    for (int nt = 0; nt < 2; ++nt) {
        float sums[4];
#pragma unroll
        for (int q = 0; q < 4; ++q) {
            float sv = 0.0f;
#pragma unroll
            for (int r = 0; r < 4; ++r)
                sv += acc[2*q][nt][r] + acc[2*q + 1][nt][r];
            sv += __shfl_xor(sv, 16, 64);
            sv += __shfl_xor(sv, 32, 64);
            sums[q] = sv;
        }
        if (lane < 16) {
            const int ch = nbase + nt*16 + lane;
            const float bb = b2[ch];
#pragma unroll
            for (int q = 0; q < 4; ++q)
                out[(size_t)(tk0 + q) * HID + ch] = fmaf(sums[q], 1.0f / KK, bb);
        }
    }
}

extern "C" void kernel_launch(void* const* d_in, const int* in_sizes, int n_in,
                              void* d_out, int out_size, void* d_ws, size_t ws_size,
                              hipStream_t stream) {
    const float* pos  = (const float*)d_in[0];
    const int*   sni  = (const int*)  d_in[1];
    const float* w_in = (const float*)d_in[2];
    const float* b_in = (const float*)d_in[3];
    const float* w1   = (const float*)d_in[4];
    const float* b1   = (const float*)d_in[5];
    const float* w2   = (const float*)d_in[6];
    const float* b2   = (const float*)d_in[7];
    float* out = (float*)d_out;
    __hip_bfloat16* wf = (__hip_bfloat16*)d_ws;            // 512 KB
    int* nbr_g = (int*)((char*)d_ws + 4 * WFE * 2);        // +256 KB
    (void)in_sizes; (void)n_in; (void)out_size; (void)ws_size;

    hipLaunchKernelGGL(knn_kernel, dim3(PREPB + BB * SS), dim3(256), 0, stream,
                       pos, sni, w1, w2, wf, nbr_g);
    hipLaunchKernelGGL(mlp_kernel, dim3(BB * SS / 4), dim3(512), 0, stream,
                       pos, nbr_g, w_in, b_in, b1, b2, wf, out);
}